// Round 10
// baseline (902.660 us; speedup 1.0000x reference)
//
#include <hip/hip_runtime.h>
#include <hip/hip_bf16.h>

#define D_IN 256
#define D_OUT 64

// ---------------------------------------------------------------------------
// K1: xw = x @ W   (fp32, vector ALU — no fp32 MFMA on CDNA4)
// Block = 256 threads = 4 waves. Each wave: 64 lanes = 64 output cols,
// handles 16 rows => 64 rows/block. Weight staged in LDS, swizzled so that
// 4 consecutive-k weights for one col are contiguous (one ds_read_b128,
// stride-16B sequential => conflict-free). x row pointers hoisted out of
// the k-loop. Epilogue also pre-fills out[row][col] = bias[col] so the
// scatter kernel can accumulate on top (saves a separate init dispatch).
// ---------------------------------------------------------------------------
__global__ __launch_bounds__(256) void gemm_kernel(
    const float* __restrict__ x, const float* __restrict__ w,
    float* __restrict__ xw, float* __restrict__ out,
    const float* __restrict__ bias, int n_rows) {
    __shared__ float ws[D_IN * D_OUT];  // 64 KB, swizzled [q][col][i]

    int tid = threadIdx.x;
    // stage weight: w[k*64 + c] -> ws[(k/4)*256 + c*4 + (k&3)]
    for (int idx = tid; idx < D_IN * D_OUT; idx += 256) {
        int k = idx >> 6;          // 0..255
        int c = idx & 63;          // 0..63
        ws[(k >> 2) * 256 + c * 4 + (k & 3)] = w[idx];
    }
    __syncthreads();

    int lane = tid & 63;
    int wid  = tid >> 6;                       // 0..3
    int row0 = blockIdx.x * 64 + wid * 16;

    // hoist row pointers (clamped) out of the k-loop
    const float* xrow[16];
#pragma unroll
    for (int r = 0; r < 16; ++r) {
        int row = row0 + r;
        int rc  = row < n_rows ? row : n_rows - 1;
        xrow[r] = &x[(size_t)rc * D_IN];
    }

    float acc[16];
#pragma unroll
    for (int r = 0; r < 16; ++r) acc[r] = 0.f;

    for (int q = 0; q < 64; ++q) {             // k-quad loop, k = 4q
        float4 wq = *(const float4*)&ws[q * 256 + lane * 4];
#pragma unroll
        for (int r = 0; r < 16; ++r) {
            float4 xq = *(const float4*)(xrow[r] + q * 4);
            acc[r] += xq.x * wq.x + xq.y * wq.y + xq.z * wq.z + xq.w * wq.w;
        }
    }

    float b = bias[lane];
#pragma unroll
    for (int r = 0; r < 16; ++r) {
        int row = row0 + r;
        if (row < n_rows) {
            xw[(size_t)row * D_OUT + lane]  = acc[r];
            out[(size_t)row * D_OUT + lane] = b;   // pre-fill for scatter-add
        }
    }
}

// ---------------------------------------------------------------------------
// K3: scatter-add. 16 lanes per edge, float4 per lane.
// msgs = val * xw[src]; out[dst] += msgs via f32 atomics (device scope).
// ---------------------------------------------------------------------------
__global__ __launch_bounds__(256) void spmm_kernel(
    const float4* __restrict__ xw4, const int* __restrict__ esrc,
    const int* __restrict__ edst, const float* __restrict__ eval,
    float* __restrict__ out, int n_edges) {
    int e = blockIdx.x * 16 + (threadIdx.x >> 4);
    if (e >= n_edges) return;
    int l = threadIdx.x & 15;
    int s = esrc[e];
    int d = edst[e];
    float v = eval[e];
    float4 m = xw4[(size_t)s * 16 + l];
    float* o = &out[(size_t)d * D_OUT + l * 4];
    atomicAdd(o + 0, v * m.x);
    atomicAdd(o + 1, v * m.y);
    atomicAdd(o + 2, v * m.z);
    atomicAdd(o + 3, v * m.w);
}

// ---------------------------------------------------------------------------
// K4: in-place ReLU (float4; out_size = 50000*64 divisible by 4)
// ---------------------------------------------------------------------------
__global__ __launch_bounds__(256) void relu_kernel(float4* __restrict__ out,
                                                   int n4) {
    int i = blockIdx.x * 256 + threadIdx.x;
    if (i < n4) {
        float4 v = out[i];
        v.x = fmaxf(v.x, 0.f);
        v.y = fmaxf(v.y, 0.f);
        v.z = fmaxf(v.z, 0.f);
        v.w = fmaxf(v.w, 0.f);
        out[i] = v;
    }
}

extern "C" void kernel_launch(void* const* d_in, const int* in_sizes, int n_in,
                              void* d_out, int out_size, void* d_ws, size_t ws_size,
                              hipStream_t stream) {
    const float* x    = (const float*)d_in[0];
    const int*   esrc = (const int*)d_in[1];
    const int*   edst = (const int*)d_in[2];
    const float* eval = (const float*)d_in[3];
    const float* w    = (const float*)d_in[4];
    const float* bias = (const float*)d_in[5];
    float*       out  = (float*)d_out;

    int n_nodes = in_sizes[0] / D_IN;
    int n_edges = in_sizes[1];

    float* xw = (float*)d_ws;   // n_nodes * 64 floats = 12.8 MB

    // K1: GEMM + bias pre-fill of out
    int gemm_blocks = (n_nodes + 63) / 64;
    gemm_kernel<<<gemm_blocks, 256, 0, stream>>>(x, w, xw, out, bias, n_nodes);

    // K3: scatter-add
    int spmm_blocks = (n_edges + 15) / 16;
    spmm_kernel<<<spmm_blocks, 256, 0, stream>>>((const float4*)xw, esrc, edst,
                                                 eval, out, n_edges);

    // K4: ReLU
    int n_elems = n_nodes * D_OUT;
    int n4 = n_elems / 4;
    relu_kernel<<<(n4 + 255) / 256, 256, 0, stream>>>((float4*)out, n4);
}

// Round 11
// 473.051 us; speedup vs baseline: 1.9082x; 1.9082x over previous
//
#include <hip/hip_runtime.h>
#include <hip/hip_bf16.h>

#define D_IN 256
#define D_OUT 64

// ---------------------------------------------------------------------------
// K1: xw = x @ W   (fp32, vector ALU — no fp32 MFMA on CDNA4)
// Unchanged from measured-correct round-10 kernel (minus bias prefill).
// ---------------------------------------------------------------------------
__global__ __launch_bounds__(256) void gemm_kernel(
    const float* __restrict__ x, const float* __restrict__ w,
    float* __restrict__ xw, int n_rows) {
    __shared__ float ws[D_IN * D_OUT];  // 64 KB, swizzled [q][col][i]

    int tid = threadIdx.x;
    for (int idx = tid; idx < D_IN * D_OUT; idx += 256) {
        int k = idx >> 6;
        int c = idx & 63;
        ws[(k >> 2) * 256 + c * 4 + (k & 3)] = w[idx];
    }
    __syncthreads();

    int lane = tid & 63;
    int wid  = tid >> 6;
    int row0 = blockIdx.x * 64 + wid * 16;

    const float* xrow[16];
#pragma unroll
    for (int r = 0; r < 16; ++r) {
        int row = row0 + r;
        int rc  = row < n_rows ? row : n_rows - 1;
        xrow[r] = &x[(size_t)rc * D_IN];
    }

    float acc[16];
#pragma unroll
    for (int r = 0; r < 16; ++r) acc[r] = 0.f;

    for (int q = 0; q < 64; ++q) {
        float4 wq = *(const float4*)&ws[q * 256 + lane * 4];
#pragma unroll
        for (int r = 0; r < 16; ++r) {
            float4 xq = *(const float4*)(xrow[r] + q * 4);
            acc[r] += xq.x * wq.x + xq.y * wq.y + xq.z * wq.z + xq.w * wq.w;
        }
    }

#pragma unroll
    for (int r = 0; r < 16; ++r) {
        int row = row0 + r;
        if (row < n_rows) xw[(size_t)row * D_OUT + lane] = acc[r];
    }
}

// ---------------------------------------------------------------------------
// CSR build: zero -> hist -> scan -> scatter.  All int atomics land on
// L2-resident counters (200 KB), ~800k ops total vs the old 51.2M f32.
// ---------------------------------------------------------------------------
__global__ __launch_bounds__(256) void zero_kernel(int* __restrict__ deg, int n) {
    int i = blockIdx.x * 256 + threadIdx.x;
    if (i < n) deg[i] = 0;
}

__global__ __launch_bounds__(256) void hist_kernel(
    const int* __restrict__ edst, int* __restrict__ deg, int n_edges) {
    int e = blockIdx.x * 256 + threadIdx.x;
    if (e < n_edges) atomicAdd(&deg[edst[e]], 1);
}

// Single-block exclusive scan over deg[n] -> off[n+1], and cursor = off copy.
__global__ __launch_bounds__(256) void scan_kernel(
    const int* __restrict__ deg, int* __restrict__ off,
    int* __restrict__ cursor, int n) {
    __shared__ int part[256];
    int t = threadIdx.x;
    int chunk = (n + 255) / 256;
    int lo = t * chunk;
    int hi = lo + chunk < n ? lo + chunk : n;
    int s = 0;
    for (int i = lo; i < hi; ++i) s += deg[i];
    part[t] = s;
    __syncthreads();
    // Hillis-Steele inclusive scan (double-barrier form)
    for (int d = 1; d < 256; d <<= 1) {
        int v = (t >= d) ? part[t - d] : 0;
        __syncthreads();
        part[t] += v;
        __syncthreads();
    }
    int base = (t == 0) ? 0 : part[t - 1];  // exclusive prefix of this chunk
    for (int i = lo; i < hi; ++i) {
        off[i] = base;
        cursor[i] = base;
        base += deg[i];
    }
    if (t == 255) off[n] = base;            // total = n_edges
}

// csr[slot] = {src, bitcast(val)} packed 8B for a single broadcast load later.
__global__ __launch_bounds__(256) void scatter_kernel(
    const int* __restrict__ esrc, const int* __restrict__ edst,
    const float* __restrict__ eval, int* __restrict__ cursor,
    int2* __restrict__ csr, int n_edges) {
    int e = blockIdx.x * 256 + threadIdx.x;
    if (e < n_edges) {
        int d = edst[e];
        int slot = atomicAdd(&cursor[d], 1);
        int2 p;
        p.x = esrc[e];
        p.y = __float_as_int(eval[e]);
        csr[slot] = p;
    }
}

// ---------------------------------------------------------------------------
// Gather: one wave per dst node; lane = column. acc starts at bias, edges
// accumulate in registers, ReLU fused at the store. Zero f32 atomics.
// xw-row loads: 64 lanes * 4B consecutive = one coalesced 256B request.
// csr/off loads: wave-uniform broadcast.
// ---------------------------------------------------------------------------
__global__ __launch_bounds__(256) void gather_kernel(
    const float* __restrict__ xw, const int2* __restrict__ csr,
    const int* __restrict__ off, const float* __restrict__ bias,
    float* __restrict__ out, int n_nodes) {
    int wave = threadIdx.x >> 6;
    int lane = threadIdx.x & 63;
    int n = blockIdx.x * 4 + wave;
    if (n >= n_nodes) return;
    int b = off[n];
    int e = off[n + 1];
    float acc = bias[lane];
    int i = b;
    for (; i + 1 < e; i += 2) {  // unroll-2: two independent row loads in flight
        int2 p0 = csr[i];
        int2 p1 = csr[i + 1];
        acc += __int_as_float(p0.y) * xw[(size_t)p0.x * D_OUT + lane];
        acc += __int_as_float(p1.y) * xw[(size_t)p1.x * D_OUT + lane];
    }
    if (i < e) {
        int2 p = csr[i];
        acc += __int_as_float(p.y) * xw[(size_t)p.x * D_OUT + lane];
    }
    out[(size_t)n * D_OUT + lane] = fmaxf(acc, 0.f);
}

extern "C" void kernel_launch(void* const* d_in, const int* in_sizes, int n_in,
                              void* d_out, int out_size, void* d_ws, size_t ws_size,
                              hipStream_t stream) {
    const float* x    = (const float*)d_in[0];
    const int*   esrc = (const int*)d_in[1];
    const int*   edst = (const int*)d_in[2];
    const float* eval = (const float*)d_in[3];
    const float* w    = (const float*)d_in[4];
    const float* bias = (const float*)d_in[5];
    float*       out  = (float*)d_out;

    int n_nodes = in_sizes[0] / D_IN;
    int n_edges = in_sizes[1];

    // workspace layout (~19.8 MB total)
    char* p = (char*)d_ws;
    float* xw = (float*)p;            p += (size_t)n_nodes * D_OUT * 4;
    int* deg = (int*)p;               p += (size_t)n_nodes * 4;
    int* off = (int*)p;               p += (size_t)(n_nodes + 1) * 4;
    p = (char*)(((uintptr_t)p + 7) & ~(uintptr_t)7);
    int* cursor = (int*)p;            p += (size_t)n_nodes * 4;
    p = (char*)(((uintptr_t)p + 7) & ~(uintptr_t)7);
    int2* csr = (int2*)p;

    // CSR build
    zero_kernel<<<(n_nodes + 255) / 256, 256, 0, stream>>>(deg, n_nodes);
    hist_kernel<<<(n_edges + 255) / 256, 256, 0, stream>>>(edst, deg, n_edges);
    scan_kernel<<<1, 256, 0, stream>>>(deg, off, cursor, n_nodes);
    scatter_kernel<<<(n_edges + 255) / 256, 256, 0, stream>>>(esrc, edst, eval,
                                                              cursor, csr, n_edges);
    // GEMM
    gemm_kernel<<<(n_nodes + 63) / 64, 256, 0, stream>>>(x, w, xw, n_nodes);

    // Gather + bias + ReLU (fused epilogue)
    gather_kernel<<<(n_nodes + 3) / 4, 256, 0, stream>>>(xw, csr, off, bias,
                                                         out, n_nodes);
}

// Round 12
// 356.727 us; speedup vs baseline: 2.5304x; 1.3261x over previous
//
#include <hip/hip_runtime.h>
#include <hip/hip_bf16.h>

#define D_IN 256
#define D_OUT 64

typedef __bf16 bf16x8 __attribute__((ext_vector_type(8)));
typedef float f32x4 __attribute__((ext_vector_type(4)));

// ---------------------------------------------------------------------------
// P0: transpose+split weight: w[256][64] fp32 -> wt_hi/wt_lo[64][256] bf16.
// hi = bf16(v), lo = bf16(v - hi)  (Ootomo split; residual ~2^-16)
// ---------------------------------------------------------------------------
__global__ __launch_bounds__(256) void prep_w_kernel(
    const float* __restrict__ w, __bf16* __restrict__ wt_hi,
    __bf16* __restrict__ wt_lo) {
    int i = blockIdx.x * 256 + threadIdx.x;   // [0, 16384)
    int c = i >> 8;                            // col 0..63
    int k = i & 255;                           // k   0..255
    float v = w[k * D_OUT + c];
    __bf16 h = (__bf16)v;
    wt_hi[i] = h;
    wt_lo[i] = (__bf16)(v - (float)h);
}

// ---------------------------------------------------------------------------
// K1: xw = x @ W via 3-MFMA split-bf16. Block = 4 waves; wave w owns rows
// [blk*64 + w*16, +16), all 64 cols (4 col-tiles of 16). No LDS, no barriers.
// A-frag: lane reads x[row0+(lane&15)][ks*32+(lane>>4)*8 ..+8] (32B contig),
// converts to hi/lo bf16 in-register. B-frags from wt_* (L1/L2-resident).
// C/D: col = lane&15, row = (lane>>4)*4 + j  (m89/m91-verified mapping).
// ---------------------------------------------------------------------------
__global__ __launch_bounds__(256) void gemm_mfma_kernel(
    const float* __restrict__ x, const __bf16* __restrict__ wt_hi,
    const __bf16* __restrict__ wt_lo, float* __restrict__ xw, int n_rows) {
    int lane = threadIdx.x & 63;
    int wid  = threadIdx.x >> 6;
    int row0 = blockIdx.x * 64 + wid * 16;

    int fr = lane & 15;          // A-row / B-col within fragment
    int ko = (lane >> 4) * 8;    // k-offset within 32-wide k-step

    int arow = row0 + fr;
    if (arow >= n_rows) arow = n_rows - 1;     // clamped load, store guarded
    const float* xr = x + (size_t)arow * D_IN + ko;

    f32x4 acc[4] = {{0.f, 0.f, 0.f, 0.f}, {0.f, 0.f, 0.f, 0.f},
                    {0.f, 0.f, 0.f, 0.f}, {0.f, 0.f, 0.f, 0.f}};

#pragma unroll
    for (int ks = 0; ks < 8; ++ks) {           // K = 8 steps x 32
        float4 a0 = *(const float4*)(xr + ks * 32);
        float4 a1 = *(const float4*)(xr + ks * 32 + 4);
        float av[8] = {a0.x, a0.y, a0.z, a0.w, a1.x, a1.y, a1.z, a1.w};
        bf16x8 ah, al;
#pragma unroll
        for (int j = 0; j < 8; ++j) {
            __bf16 h = (__bf16)av[j];
            ah[j] = h;
            al[j] = (__bf16)(av[j] - (float)h);
        }
#pragma unroll
        for (int ct = 0; ct < 4; ++ct) {
            const __bf16* bp = wt_hi + (size_t)(ct * 16 + fr) * D_IN + ks * 32 + ko;
            const __bf16* lp = wt_lo + (size_t)(ct * 16 + fr) * D_IN + ks * 32 + ko;
            bf16x8 bh = *(const bf16x8*)bp;
            bf16x8 bl = *(const bf16x8*)lp;
            acc[ct] = __builtin_amdgcn_mfma_f32_16x16x32_bf16(ah, bh, acc[ct], 0, 0, 0);
            acc[ct] = __builtin_amdgcn_mfma_f32_16x16x32_bf16(al, bh, acc[ct], 0, 0, 0);
            acc[ct] = __builtin_amdgcn_mfma_f32_16x16x32_bf16(ah, bl, acc[ct], 0, 0, 0);
        }
    }

    int crow0 = row0 + (lane >> 4) * 4;
#pragma unroll
    for (int ct = 0; ct < 4; ++ct) {
        int col = ct * 16 + fr;
#pragma unroll
        for (int j = 0; j < 4; ++j) {
            int row = crow0 + j;
            if (row < n_rows) xw[(size_t)row * D_OUT + col] = acc[ct][j];
        }
    }
}

// ---------------------------------------------------------------------------
// CSR build: zero -> hist -> scan -> scatter (int atomics on L2-resident data)
// ---------------------------------------------------------------------------
__global__ __launch_bounds__(256) void zero_kernel(int* __restrict__ deg, int n) {
    int i = blockIdx.x * 256 + threadIdx.x;
    if (i < n) deg[i] = 0;
}

__global__ __launch_bounds__(256) void hist_kernel(
    const int* __restrict__ edst, int* __restrict__ deg, int n_edges) {
    int e = blockIdx.x * 256 + threadIdx.x;
    if (e < n_edges) atomicAdd(&deg[edst[e]], 1);
}

// Single-block (1024 thr) exclusive scan: deg[n] -> off[n+1], cursor = off.
__global__ __launch_bounds__(1024) void scan_kernel(
    const int* __restrict__ deg, int* __restrict__ off,
    int* __restrict__ cursor, int n) {
    __shared__ int part[1024];
    int t = threadIdx.x;
    int chunk = (n + 1023) / 1024;
    int lo = t * chunk;
    int hi = lo + chunk < n ? lo + chunk : n;
    int s = 0;
    for (int i = lo; i < hi; ++i) s += deg[i];
    part[t] = s;
    __syncthreads();
    for (int d = 1; d < 1024; d <<= 1) {       // Hillis-Steele inclusive
        int v = (t >= d) ? part[t - d] : 0;
        __syncthreads();
        part[t] += v;
        __syncthreads();
    }
    int base = (t == 0) ? 0 : part[t - 1];
    for (int i = lo; i < hi; ++i) {
        off[i] = base;
        cursor[i] = base;
        base += deg[i];
    }
    if (t == 1023) off[n] = base;
}

__global__ __launch_bounds__(256) void scatter_kernel(
    const int* __restrict__ esrc, const int* __restrict__ edst,
    const float* __restrict__ eval, int* __restrict__ cursor,
    int2* __restrict__ csr, int n_edges) {
    int e = blockIdx.x * 256 + threadIdx.x;
    if (e < n_edges) {
        int d = edst[e];
        int slot = atomicAdd(&cursor[d], 1);
        int2 p;
        p.x = esrc[e];
        p.y = __float_as_int(eval[e]);
        csr[slot] = p;
    }
}

// ---------------------------------------------------------------------------
// Gather: one wave per dst node; lane = column; unroll-4 for MLP latency.
// acc starts at bias; ReLU fused at store. Zero f32 atomics.
// ---------------------------------------------------------------------------
__global__ __launch_bounds__(256) void gather_kernel(
    const float* __restrict__ xw, const int2* __restrict__ csr,
    const int* __restrict__ off, const float* __restrict__ bias,
    float* __restrict__ out, int n_nodes) {
    int wave = threadIdx.x >> 6;
    int lane = threadIdx.x & 63;
    int n = blockIdx.x * 4 + wave;
    if (n >= n_nodes) return;
    int b = off[n];
    int e = off[n + 1];
    float acc = bias[lane];
    int i = b;
    for (; i + 3 < e; i += 4) {
        int2 p0 = csr[i], p1 = csr[i + 1], p2 = csr[i + 2], p3 = csr[i + 3];
        float m0 = xw[(size_t)p0.x * D_OUT + lane];
        float m1 = xw[(size_t)p1.x * D_OUT + lane];
        float m2 = xw[(size_t)p2.x * D_OUT + lane];
        float m3 = xw[(size_t)p3.x * D_OUT + lane];
        acc += __int_as_float(p0.y) * m0 + __int_as_float(p1.y) * m1 +
               __int_as_float(p2.y) * m2 + __int_as_float(p3.y) * m3;
    }
    for (; i < e; ++i) {
        int2 p = csr[i];
        acc += __int_as_float(p.y) * xw[(size_t)p.x * D_OUT + lane];
    }
    out[(size_t)n * D_OUT + lane] = fmaxf(acc, 0.f);
}

extern "C" void kernel_launch(void* const* d_in, const int* in_sizes, int n_in,
                              void* d_out, int out_size, void* d_ws, size_t ws_size,
                              hipStream_t stream) {
    const float* x    = (const float*)d_in[0];
    const int*   esrc = (const int*)d_in[1];
    const int*   edst = (const int*)d_in[2];
    const float* eval = (const float*)d_in[3];
    const float* w    = (const float*)d_in[4];
    const float* bias = (const float*)d_in[5];
    float*       out  = (float*)d_out;

    int n_nodes = in_sizes[0] / D_IN;
    int n_edges = in_sizes[1];

    // workspace layout (~19.9 MB)
    char* p = (char*)d_ws;
    float* xw = (float*)p;            p += (size_t)n_nodes * D_OUT * 4;
    __bf16* wt_hi = (__bf16*)p;       p += (size_t)D_IN * D_OUT * 2;
    __bf16* wt_lo = (__bf16*)p;       p += (size_t)D_IN * D_OUT * 2;
    int* deg = (int*)p;               p += (size_t)n_nodes * 4;
    int* off = (int*)p;               p += (size_t)(n_nodes + 1) * 4;
    p = (char*)(((uintptr_t)p + 7) & ~(uintptr_t)7);
    int* cursor = (int*)p;            p += (size_t)n_nodes * 4;
    p = (char*)(((uintptr_t)p + 7) & ~(uintptr_t)7);
    int2* csr = (int2*)p;

    // weight prep + CSR build
    prep_w_kernel<<<(D_IN * D_OUT + 255) / 256, 256, 0, stream>>>(w, wt_hi, wt_lo);
    zero_kernel<<<(n_nodes + 255) / 256, 256, 0, stream>>>(deg, n_nodes);
    hist_kernel<<<(n_edges + 255) / 256, 256, 0, stream>>>(edst, deg, n_edges);
    scan_kernel<<<1, 1024, 0, stream>>>(deg, off, cursor, n_nodes);
    scatter_kernel<<<(n_edges + 255) / 256, 256, 0, stream>>>(esrc, edst, eval,
                                                              cursor, csr, n_edges);
    // GEMM (MFMA split-bf16)
    gemm_mfma_kernel<<<(n_nodes + 63) / 64, 256, 0, stream>>>(x, wt_hi, wt_lo,
                                                              xw, n_nodes);
    // Gather + bias + ReLU
    gather_kernel<<<(n_nodes + 3) / 4, 256, 0, stream>>>(xw, csr, off, bias,
                                                         out, n_nodes);
}

// Round 14
// 258.378 us; speedup vs baseline: 3.4936x; 1.3806x over previous
//
#include <hip/hip_runtime.h>
#include <hip/hip_bf16.h>

#define D_IN 256
#define D_OUT 64

typedef __bf16 bf16x8 __attribute__((ext_vector_type(8)));
typedef float f32x4 __attribute__((ext_vector_type(4)));

// ---------------------------------------------------------------------------
// P0: transpose+split weight: w[256][64] fp32 -> wt_hi/wt_lo[64][256] bf16.
// ---------------------------------------------------------------------------
__global__ __launch_bounds__(256) void prep_w_kernel(
    const float* __restrict__ w, __bf16* __restrict__ wt_hi,
    __bf16* __restrict__ wt_lo) {
    int i = blockIdx.x * 256 + threadIdx.x;   // [0, 16384)
    int c = i >> 8;                            // col 0..63
    int k = i & 255;                           // k   0..255
    float v = w[k * D_OUT + c];
    __bf16 h = (__bf16)v;
    wt_hi[i] = h;
    wt_lo[i] = (__bf16)(v - (float)h);
}

// ---------------------------------------------------------------------------
// K1: xw = x @ W via 3-MFMA split-bf16 (measured: left top-5, ~30us).
// ---------------------------------------------------------------------------
__global__ __launch_bounds__(256) void gemm_mfma_kernel(
    const float* __restrict__ x, const __bf16* __restrict__ wt_hi,
    const __bf16* __restrict__ wt_lo, float* __restrict__ xw, int n_rows) {
    int lane = threadIdx.x & 63;
    int wid  = threadIdx.x >> 6;
    int row0 = blockIdx.x * 64 + wid * 16;

    int fr = lane & 15;
    int ko = (lane >> 4) * 8;

    int arow = row0 + fr;
    if (arow >= n_rows) arow = n_rows - 1;
    const float* xr = x + (size_t)arow * D_IN + ko;

    f32x4 acc[4] = {{0.f, 0.f, 0.f, 0.f}, {0.f, 0.f, 0.f, 0.f},
                    {0.f, 0.f, 0.f, 0.f}, {0.f, 0.f, 0.f, 0.f}};

#pragma unroll
    for (int ks = 0; ks < 8; ++ks) {
        float4 a0 = *(const float4*)(xr + ks * 32);
        float4 a1 = *(const float4*)(xr + ks * 32 + 4);
        float av[8] = {a0.x, a0.y, a0.z, a0.w, a1.x, a1.y, a1.z, a1.w};
        bf16x8 ah, al;
#pragma unroll
        for (int j = 0; j < 8; ++j) {
            __bf16 h = (__bf16)av[j];
            ah[j] = h;
            al[j] = (__bf16)(av[j] - (float)h);
        }
#pragma unroll
        for (int ct = 0; ct < 4; ++ct) {
            const __bf16* bp = wt_hi + (size_t)(ct * 16 + fr) * D_IN + ks * 32 + ko;
            const __bf16* lp = wt_lo + (size_t)(ct * 16 + fr) * D_IN + ks * 32 + ko;
            bf16x8 bh = *(const bf16x8*)bp;
            bf16x8 bl = *(const bf16x8*)lp;
            acc[ct] = __builtin_amdgcn_mfma_f32_16x16x32_bf16(ah, bh, acc[ct], 0, 0, 0);
            acc[ct] = __builtin_amdgcn_mfma_f32_16x16x32_bf16(al, bh, acc[ct], 0, 0, 0);
            acc[ct] = __builtin_amdgcn_mfma_f32_16x16x32_bf16(ah, bl, acc[ct], 0, 0, 0);
        }
    }

    int crow0 = row0 + (lane >> 4) * 4;
#pragma unroll
    for (int ct = 0; ct < 4; ++ct) {
        int col = ct * 16 + fr;
#pragma unroll
        for (int j = 0; j < 4; ++j) {
            int row = crow0 + j;
            if (row < n_rows) xw[(size_t)row * D_OUT + col] = acc[ct][j];
        }
    }
}

// ---------------------------------------------------------------------------
// CSR build: zero -> hist -> 3-phase scan -> scatter
// ---------------------------------------------------------------------------
__global__ __launch_bounds__(256) void zero_kernel(int* __restrict__ deg, int n) {
    int i = blockIdx.x * 256 + threadIdx.x;
    if (i < n) deg[i] = 0;
}

__global__ __launch_bounds__(256) void hist_kernel(
    const int* __restrict__ edst, int* __restrict__ deg, int n_edges) {
    int e = blockIdx.x * 256 + threadIdx.x;
    if (e < n_edges) atomicAdd(&deg[edst[e]], 1);
}

// Phase 1: per-block (256-tile) sums.
__global__ __launch_bounds__(256) void scan_partial_kernel(
    const int* __restrict__ deg, int* __restrict__ part, int n) {
    __shared__ int lds[256];
    int t = threadIdx.x;
    int i = blockIdx.x * 256 + t;
    lds[t] = (i < n) ? deg[i] : 0;
    __syncthreads();
    for (int s = 128; s > 0; s >>= 1) {
        if (t < s) lds[t] += lds[t + s];
        __syncthreads();
    }
    if (t == 0) part[blockIdx.x] = lds[0];
}

// Phase 2: single block, exclusive scan of nblk (<=256) partials in-place.
__global__ __launch_bounds__(256) void scan_base_kernel(
    int* __restrict__ part, int nblk) {
    __shared__ int lds[256];
    int t = threadIdx.x;
    lds[t] = (t < nblk) ? part[t] : 0;
    __syncthreads();
    for (int d = 1; d < 256; d <<= 1) {         // Hillis-Steele inclusive
        int v = (t >= d) ? lds[t - d] : 0;
        __syncthreads();
        lds[t] += v;
        __syncthreads();
    }
    if (t < nblk) part[t] = (t == 0) ? 0 : lds[t - 1];   // exclusive
}

// Phase 3: in-tile inclusive scan + block base -> off/cursor; off[n] from tail.
__global__ __launch_bounds__(256) void scan_final_kernel(
    const int* __restrict__ deg, const int* __restrict__ part,
    int* __restrict__ off, int* __restrict__ cursor, int n) {
    __shared__ int lds[256];
    int t = threadIdx.x;
    int i = blockIdx.x * 256 + t;
    int v = (i < n) ? deg[i] : 0;
    lds[t] = v;
    __syncthreads();
    for (int d = 1; d < 256; d <<= 1) {         // Hillis-Steele inclusive
        int u = (t >= d) ? lds[t - d] : 0;
        __syncthreads();
        lds[t] += u;
        __syncthreads();
    }
    int val = part[blockIdx.x] + lds[t] - v;    // exclusive prefix
    if (i < n) {
        off[i] = val;
        cursor[i] = val;
        if (i == n - 1) off[n] = val + v;
    }
}

__global__ __launch_bounds__(256) void scatter_kernel(
    const int* __restrict__ esrc, const int* __restrict__ edst,
    const float* __restrict__ eval, int* __restrict__ cursor,
    int2* __restrict__ csr, int n_edges) {
    int e = blockIdx.x * 256 + threadIdx.x;
    if (e < n_edges) {
        int d = edst[e];
        int slot = atomicAdd(&cursor[d], 1);
        int2 p;
        p.x = esrc[e];
        p.y = __float_as_int(eval[e]);
        csr[slot] = p;
    }
}

// ---------------------------------------------------------------------------
// Gather: one wave per dst node; lane = column; unroll-4. (unchanged)
// ---------------------------------------------------------------------------
__global__ __launch_bounds__(256) void gather_kernel(
    const float* __restrict__ xw, const int2* __restrict__ csr,
    const int* __restrict__ off, const float* __restrict__ bias,
    float* __restrict__ out, int n_nodes) {
    int wave = threadIdx.x >> 6;
    int lane = threadIdx.x & 63;
    int n = blockIdx.x * 4 + wave;
    if (n >= n_nodes) return;
    int b = off[n];
    int e = off[n + 1];
    float acc = bias[lane];
    int i = b;
    for (; i + 3 < e; i += 4) {
        int2 p0 = csr[i], p1 = csr[i + 1], p2 = csr[i + 2], p3 = csr[i + 3];
        float m0 = xw[(size_t)p0.x * D_OUT + lane];
        float m1 = xw[(size_t)p1.x * D_OUT + lane];
        float m2 = xw[(size_t)p2.x * D_OUT + lane];
        float m3 = xw[(size_t)p3.x * D_OUT + lane];
        acc += __int_as_float(p0.y) * m0 + __int_as_float(p1.y) * m1 +
               __int_as_float(p2.y) * m2 + __int_as_float(p3.y) * m3;
    }
    for (; i < e; ++i) {
        int2 p = csr[i];
        acc += __int_as_float(p.y) * xw[(size_t)p.x * D_OUT + lane];
    }
    out[(size_t)n * D_OUT + lane] = fmaxf(acc, 0.f);
}

extern "C" void kernel_launch(void* const* d_in, const int* in_sizes, int n_in,
                              void* d_out, int out_size, void* d_ws, size_t ws_size,
                              hipStream_t stream) {
    const float* x    = (const float*)d_in[0];
    const int*   esrc = (const int*)d_in[1];
    const int*   edst = (const int*)d_in[2];
    const float* eval = (const float*)d_in[3];
    const float* w    = (const float*)d_in[4];
    const float* bias = (const float*)d_in[5];
    float*       out  = (float*)d_out;

    int n_nodes = in_sizes[0] / D_IN;
    int n_edges = in_sizes[1];
    int nblk = (n_nodes + 255) / 256;          // 196 <= 256 (scan_base capacity)

    // workspace layout (~19.9 MB)
    char* p = (char*)d_ws;
    float* xw = (float*)p;            p += (size_t)n_nodes * D_OUT * 4;
    __bf16* wt_hi = (__bf16*)p;       p += (size_t)D_IN * D_OUT * 2;
    __bf16* wt_lo = (__bf16*)p;       p += (size_t)D_IN * D_OUT * 2;
    int* deg = (int*)p;               p += (size_t)n_nodes * 4;
    int* off = (int*)p;               p += (size_t)(n_nodes + 1) * 4;
    int* part = (int*)p;              p += (size_t)nblk * 4;
    p = (char*)(((uintptr_t)p + 7) & ~(uintptr_t)7);
    int* cursor = (int*)p;            p += (size_t)n_nodes * 4;
    p = (char*)(((uintptr_t)p + 7) & ~(uintptr_t)7);
    int2* csr = (int2*)p;

    // weight prep + CSR build
    prep_w_kernel<<<(D_IN * D_OUT + 255) / 256, 256, 0, stream>>>(w, wt_hi, wt_lo);
    zero_kernel<<<nblk, 256, 0, stream>>>(deg, n_nodes);
    hist_kernel<<<(n_edges + 255) / 256, 256, 0, stream>>>(edst, deg, n_edges);
    scan_partial_kernel<<<nblk, 256, 0, stream>>>(deg, part, n_nodes);
    scan_base_kernel<<<1, 256, 0, stream>>>(part, nblk);
    scan_final_kernel<<<nblk, 256, 0, stream>>>(deg, part, off, cursor, n_nodes);
    scatter_kernel<<<(n_edges + 255) / 256, 256, 0, stream>>>(esrc, edst, eval,
                                                              cursor, csr, n_edges);
    // GEMM (MFMA split-bf16)
    gemm_mfma_kernel<<<(n_nodes + 63) / 64, 256, 0, stream>>>(x, wt_hi, wt_lo,
                                                              xw, n_nodes);
    // Gather + bias + ReLU
    gather_kernel<<<(n_nodes + 3) / 4, 256, 0, stream>>>(xw, csr, off, bias,
                                                         out, n_nodes);
}